// Round 1
// baseline (354.418 us; speedup 1.0000x reference)
//
#include <hip/hip_runtime.h>

// GCN layer: out = D^-1/2 (A + I) D^-1/2 (X W) + b
// N=50000 nodes, E=800000 edges, 128 channels, fp32.

constexpr int CH = 128;

// ---- CSR build ----------------------------------------------------------

__global__ void count_kernel(const int* __restrict__ dst, int* __restrict__ cnt, int E) {
    int e = blockIdx.x * blockDim.x + threadIdx.x;
    if (e < E) atomicAdd(&cnt[dst[e]], 1);
}

// single-block exclusive scan of cnt[0..N) -> off[0..N], off[N] = E; cur = copy of off
__global__ void scan_kernel(const int* __restrict__ cnt, int* __restrict__ off,
                            int* __restrict__ cur, int N) {
    __shared__ int sm[1024];
    __shared__ int carry_s;
    if (threadIdx.x == 0) carry_s = 0;
    __syncthreads();
    int total = N + 1;
    for (int base = 0; base < total; base += 1024) {
        int i = base + (int)threadIdx.x;
        int v = (i < N) ? cnt[i] : 0;
        sm[threadIdx.x] = v;
        __syncthreads();
        for (int d = 1; d < 1024; d <<= 1) {
            int t = (threadIdx.x >= (unsigned)d) ? sm[threadIdx.x - d] : 0;
            __syncthreads();
            sm[threadIdx.x] += t;
            __syncthreads();
        }
        int excl = sm[threadIdx.x] - v + carry_s;
        if (i < N) { off[i] = excl; cur[i] = excl; }
        else if (i == N) { off[N] = excl; }
        __syncthreads();
        if (threadIdx.x == 1023) carry_s += sm[1023];
        __syncthreads();
    }
}

__global__ void dinv_kernel(const int* __restrict__ cnt, float* __restrict__ dinv, int N) {
    int i = blockIdx.x * blockDim.x + threadIdx.x;
    if (i < N) dinv[i] = rsqrtf((float)(cnt[i] + 1));  // +1 self loop; deg >= 1 always
}

__global__ void fill_kernel(const int* __restrict__ src, const int* __restrict__ dst,
                            int* __restrict__ cur, int* __restrict__ csr, int E) {
    int e = blockIdx.x * blockDim.x + threadIdx.x;
    if (e < E) {
        int p = atomicAdd(&cur[dst[e]], 1);
        csr[p] = src[e];
    }
}

// ---- GEMM: xw = x @ W  (fp32, LDS-staged W in K-halves) -----------------

__global__ __launch_bounds__(256) void gemm_kernel(const float* __restrict__ x,
                                                   const float* __restrict__ Wm,
                                                   float* __restrict__ xw, int N) {
    // 8 nodes / block; 32 threads per node; each thread computes 4 channels.
    __shared__ float Ws[64][CH];   // 32 KB (half of K at a time)
    __shared__ float xs[8][132];   // padded: stride 132 -> bank offset 4 per node row
    int t = threadIdx.x;
    int g = t >> 5;       // node group within block (0..7)
    int l = t & 31;       // lane in group; channels l*4 .. l*4+3
    int node0 = blockIdx.x * 8;
    int node = node0 + g;

    // stage x rows: 1024 floats, 4 per thread
    {
        int idx = t * 4;
        int nn = idx >> 7, cc = idx & 127;
        int gn = node0 + nn;
        float4 v = make_float4(0.f, 0.f, 0.f, 0.f);
        if (gn < N) v = *(const float4*)&x[(size_t)gn * CH + cc];
        xs[nn][cc] = v.x; xs[nn][cc + 1] = v.y; xs[nn][cc + 2] = v.z; xs[nn][cc + 3] = v.w;
    }

    float4 acc = make_float4(0.f, 0.f, 0.f, 0.f);
    for (int ko = 0; ko < CH; ko += 64) {
        __syncthreads();
        // stage W[ko..ko+64)[:] : 8192 floats, 32 per thread (8x float4)
        #pragma unroll
        for (int r = 0; r < 8; ++r) {
            int idx = (r * 256 + t) * 4;    // 0..8191
            int kk = idx >> 7, cc = idx & 127;
            float4 v = *(const float4*)&Wm[(size_t)(ko + kk) * CH + cc];
            Ws[kk][cc] = v.x; Ws[kk][cc + 1] = v.y; Ws[kk][cc + 2] = v.z; Ws[kk][cc + 3] = v.w;
        }
        __syncthreads();
        #pragma unroll
        for (int k = 0; k < 64; ++k) {
            float xv = xs[g][ko + k];
            float4 wv = *(const float4*)&Ws[k][l * 4];
            acc.x += xv * wv.x; acc.y += xv * wv.y;
            acc.z += xv * wv.z; acc.w += xv * wv.w;
        }
    }
    if (node < N) *(float4*)&xw[(size_t)node * CH + l * 4] = acc;
}

// ---- Aggregation: out[i] = di * sum_j dinv[src_j]*xw[src_j] + di^2*xw[i] + b

__global__ __launch_bounds__(256) void agg_kernel(const float* __restrict__ xw,
                                                  const int* __restrict__ csr,
                                                  const int* __restrict__ off,
                                                  const float* __restrict__ dinv,
                                                  const float* __restrict__ b,
                                                  float* __restrict__ out, int N) {
    int g = threadIdx.x >> 5, l = threadIdx.x & 31;
    int node = blockIdx.x * 8 + g;
    if (node >= N) return;
    int s = off[node], e = off[node + 1];
    float4 acc = make_float4(0.f, 0.f, 0.f, 0.f);
    for (int j = s; j < e; ++j) {
        int sr = csr[j];
        float w = dinv[sr];
        float4 v = *(const float4*)&xw[(size_t)sr * CH + l * 4];
        acc.x += w * v.x; acc.y += w * v.y; acc.z += w * v.z; acc.w += w * v.w;
    }
    float di = dinv[node];
    float dii = di * di;
    float4 sv = *(const float4*)&xw[(size_t)node * CH + l * 4];
    float4 bv = *(const float4*)&b[l * 4];
    float4 r;
    r.x = di * acc.x + dii * sv.x + bv.x;
    r.y = di * acc.y + dii * sv.y + bv.y;
    r.z = di * acc.z + dii * sv.z + bv.z;
    r.w = di * acc.w + dii * sv.w + bv.w;
    *(float4*)&out[(size_t)node * CH + l * 4] = r;
}

// ---- launch -------------------------------------------------------------

extern "C" void kernel_launch(void* const* d_in, const int* in_sizes, int n_in,
                              void* d_out, int out_size, void* d_ws, size_t ws_size,
                              hipStream_t stream) {
    const float* x  = (const float*)d_in[0];
    const float* Wm = (const float*)d_in[1];
    const float* b  = (const float*)d_in[2];
    const int*   ei = (const int*)d_in[3];
    int N = in_sizes[0] / CH;
    int E = in_sizes[3] / 2;
    const int* src = ei;
    const int* dst = ei + E;
    float* out = (float*)d_out;

    char* w = (char*)d_ws;
    auto alloc = [&](size_t bytes) {
        char* p = w;
        w += (bytes + 255) & ~(size_t)255;
        return p;
    };
    float* xw   = (float*)alloc((size_t)N * CH * 4);
    int*   cnt  = (int*)alloc((size_t)N * 4);
    int*   off  = (int*)alloc((size_t)(N + 1) * 4);
    int*   cur  = (int*)alloc((size_t)N * 4);
    int*   csr  = (int*)alloc((size_t)E * 4);
    float* dinv = (float*)alloc((size_t)N * 4);

    hipMemsetAsync(cnt, 0, (size_t)N * 4, stream);
    count_kernel<<<(E + 255) / 256, 256, 0, stream>>>(dst, cnt, E);
    scan_kernel<<<1, 1024, 0, stream>>>(cnt, off, cur, N);
    dinv_kernel<<<(N + 255) / 256, 256, 0, stream>>>(cnt, dinv, N);
    fill_kernel<<<(E + 255) / 256, 256, 0, stream>>>(src, dst, cur, csr, E);
    gemm_kernel<<<(N + 7) / 8, 256, 0, stream>>>(x, Wm, xw, N);
    agg_kernel<<<(N + 7) / 8, 256, 0, stream>>>(xw, csr, off, dinv, b, out, N);
}

// Round 2
// 260.230 us; speedup vs baseline: 1.3619x; 1.3619x over previous
//
#include <hip/hip_runtime.h>

// GCN layer: out = D^-1/2 (A + I) D^-1/2 (X W) + b
// N=50000, E=800000, 128 ch. MFMA bf16 GEMM + fused dinv scaling + bf16 gather table.

constexpr int CH = 128;

typedef __attribute__((ext_vector_type(8))) short short8;
typedef __attribute__((ext_vector_type(4))) float f32x4;

static __device__ __forceinline__ ushort f2bf(float f) {
    unsigned u = __float_as_uint(f);
    u += 0x7fff + ((u >> 16) & 1);   // RNE
    return (ushort)(u >> 16);
}

// ---- CSR build ----------------------------------------------------------

__global__ void count_kernel(const int* __restrict__ dst, int* __restrict__ cnt, int E) {
    int e = blockIdx.x * blockDim.x + threadIdx.x;
    if (e < E) atomicAdd(&cnt[dst[e]], 1);
}

// single block: per-thread serial chunk sums + one LDS scan of 1024 partials
__global__ __launch_bounds__(1024) void scan_kernel(const int* __restrict__ cnt,
                                                    int* __restrict__ off,
                                                    int* __restrict__ cur, int N) {
    __shared__ int part[1024];
    int t = threadIdx.x;
    int chunk = (N + 1023) / 1024;
    int s = t * chunk;
    int e = s + chunk; if (e > N) e = N; if (s > N) s = N;
    int sum = 0;
    for (int i = s; i < e; ++i) sum += cnt[i];
    part[t] = sum;
    __syncthreads();
    for (int d = 1; d < 1024; d <<= 1) {
        int v = (t >= d) ? part[t - d] : 0;
        __syncthreads();
        part[t] += v;
        __syncthreads();
    }
    int run = part[t] - sum;   // exclusive prefix
    for (int i = s; i < e; ++i) {
        off[i] = run; cur[i] = run;
        run += cnt[i];
    }
    if (t == 1023) off[N] = run;   // == E
}

__global__ void dinv_kernel(const int* __restrict__ cnt, float* __restrict__ dinv, int N) {
    int i = blockIdx.x * blockDim.x + threadIdx.x;
    if (i < N) dinv[i] = rsqrtf((float)(cnt[i] + 1));  // +1 self loop
}

__global__ void fill_kernel(const int* __restrict__ src, const int* __restrict__ dst,
                            int* __restrict__ cur, int* __restrict__ csr, int E) {
    int e = blockIdx.x * blockDim.x + threadIdx.x;
    if (e < E) {
        int p = atomicAdd(&cur[dst[e]], 1);
        csr[p] = src[e];
    }
}

// ---- W pre-pack: fp32 [128][128] -> bf16 transposed, XOR-swizzled -------
// Layout: 16B chunk index idx16 = col*16 + (k>>3), swizzled idx16 ^= (col&7).
// Chunk holds W[k0..k0+7][col] contiguous (B-fragment for mfma 16x16x32).

__global__ void pack_w(const float* __restrict__ W, ushort* __restrict__ Wp) {
    int tid = blockIdx.x * blockDim.x + threadIdx.x;   // 2048 threads
    if (tid >= 2048) return;
    int col = tid >> 4, chunk = tid & 15;
    ushort tmp[8];
    #pragma unroll
    for (int i = 0; i < 8; ++i)
        tmp[i] = f2bf(W[(size_t)(chunk * 8 + i) * CH + col]);
    int d = col * 16 + (chunk ^ (col & 7));
    *(uint4*)&Wp[(size_t)d * 8] = *(uint4*)tmp;
}

// ---- GEMM: xwd[r][:] = (x[r][:] @ W) * dinv[r], bf16 out ----------------

__global__ __launch_bounds__(256) void gemm_mfma(const float* __restrict__ x,
        const ushort* __restrict__ Wp, const float* __restrict__ dinv,
        ushort* __restrict__ xwd, int N) {
    __shared__ alignas(16) ushort Wlds[16384];   // 32 KB
    int t = threadIdx.x;
    int wv = t >> 6, l = t & 63;
    int c15 = l & 15, kc = l >> 4;               // kc in 0..3
    int row0 = blockIdx.x * 64 + wv * 16;
    int r = row0 + c15;
    bool valid = r < N;

    // A fragments: af[ks] = x[r][ks*32 + kc*8 .. +7] as bf16
    short8 af[4];
    #pragma unroll
    for (int ks = 0; ks < 4; ++ks) {
        float4 a0 = make_float4(0.f,0.f,0.f,0.f), a1 = a0;
        if (valid) {
            const float* p = x + (size_t)r * CH + ks * 32 + kc * 8;
            a0 = *(const float4*)p;
            a1 = *(const float4*)(p + 4);
        }
        short8 v;
        v[0]=f2bf(a0.x); v[1]=f2bf(a0.y); v[2]=f2bf(a0.z); v[3]=f2bf(a0.w);
        v[4]=f2bf(a1.x); v[5]=f2bf(a1.y); v[6]=f2bf(a1.z); v[7]=f2bf(a1.w);
        af[ks] = v;
    }

    // stage packed W (32 KB) into LDS, linear
    #pragma unroll
    for (int i = 0; i < 8; ++i) {
        int idx = i * 256 + t;
        *(uint4*)&Wlds[idx * 8] = *(const uint4*)&Wp[idx * 8];
    }
    __syncthreads();

    f32x4 acc[8];
    #pragma unroll
    for (int ct = 0; ct < 8; ++ct) { f32x4 z = {0.f,0.f,0.f,0.f}; acc[ct] = z; }

    int swz = l & 7;
    #pragma unroll
    for (int ks = 0; ks < 4; ++ks) {
        #pragma unroll
        for (int ct = 0; ct < 8; ++ct) {
            int col = ct * 16 + c15;
            int idx16 = (col * 16 + ks * 4 + kc) ^ swz;
            short8 bfrag = *(const short8*)&Wlds[idx16 * 8];
            acc[ct] = __builtin_amdgcn_mfma_f32_16x16x32_bf16(af[ks], bfrag, acc[ct], 0, 0, 0);
        }
    }

    // dinv for this lane's 4 output rows (C/D: row = kc*4 + reg, col = ct*16 + c15)
    float dv[4];
    #pragma unroll
    for (int rr = 0; rr < 4; ++rr) {
        int row = row0 + kc * 4 + rr;
        dv[rr] = (row < N) ? dinv[row] : 0.f;
    }
    __syncthreads();   // all waves done reading Wlds; reuse as bounce buffer

    ushort* bw = Wlds + wv * 2048;   // 16 rows x 128 cols bf16 per wave
    #pragma unroll
    for (int ct = 0; ct < 8; ++ct) {
        #pragma unroll
        for (int rr = 0; rr < 4; ++rr) {
            int row_local = kc * 4 + rr;
            bw[row_local * CH + ct * 16 + c15] = f2bf(acc[ct][rr] * dv[rr]);
        }
    }
    // wave-local readback -> coalesced 16B global stores
    #pragma unroll
    for (int p = 0; p < 4; ++p) {
        int row_local = p * 4 + kc;
        int row = row0 + row_local;
        if (row < N) {
            uint4 vv = *(const uint4*)&bw[row_local * CH + c15 * 8];
            *(uint4*)&xwd[(size_t)row * CH + c15 * 8] = vv;
        }
    }
}

// ---- Aggregation: out[i] = dinv[i] * (sum_j xwd[src_j] + xwd[i]) + b ----

__global__ __launch_bounds__(256) void agg_kernel(const ushort* __restrict__ xwd,
        const int* __restrict__ csr, const int* __restrict__ off,
        const float* __restrict__ dinv, const float* __restrict__ b,
        float* __restrict__ out, int N) {
    int t = threadIdx.x;
    int c15 = t & 15;                      // 16 lanes/node, 8 ch each
    int node = blockIdx.x * 16 + (t >> 4);
    if (node >= N) return;
    int s = off[node], e = off[node + 1];
    float acc[8] = {0.f,0.f,0.f,0.f,0.f,0.f,0.f,0.f};
    const ushort* base = xwd + c15 * 8;

    int sr = (s < e) ? csr[s] : node;
    for (int j = s; j < e; ++j) {
        int nsr = (j + 1 < e) ? csr[j + 1] : node;   // prefetch next index
        uint4 v = *(const uint4*)(base + (size_t)sr * CH);
        acc[0] += __uint_as_float(v.x << 16);
        acc[1] += __uint_as_float(v.x & 0xffff0000u);
        acc[2] += __uint_as_float(v.y << 16);
        acc[3] += __uint_as_float(v.y & 0xffff0000u);
        acc[4] += __uint_as_float(v.z << 16);
        acc[5] += __uint_as_float(v.z & 0xffff0000u);
        acc[6] += __uint_as_float(v.w << 16);
        acc[7] += __uint_as_float(v.w & 0xffff0000u);
        sr = nsr;
    }
    {   // self loop term
        uint4 v = *(const uint4*)(base + (size_t)node * CH);
        acc[0] += __uint_as_float(v.x << 16);
        acc[1] += __uint_as_float(v.x & 0xffff0000u);
        acc[2] += __uint_as_float(v.y << 16);
        acc[3] += __uint_as_float(v.y & 0xffff0000u);
        acc[4] += __uint_as_float(v.z << 16);
        acc[5] += __uint_as_float(v.z & 0xffff0000u);
        acc[6] += __uint_as_float(v.w << 16);
        acc[7] += __uint_as_float(v.w & 0xffff0000u);
    }
    float di = dinv[node];
    float4 b0 = *(const float4*)&b[c15 * 8];
    float4 b1 = *(const float4*)&b[c15 * 8 + 4];
    float4 o0, o1;
    o0.x = di * acc[0] + b0.x;  o0.y = di * acc[1] + b0.y;
    o0.z = di * acc[2] + b0.z;  o0.w = di * acc[3] + b0.w;
    o1.x = di * acc[4] + b1.x;  o1.y = di * acc[5] + b1.y;
    o1.z = di * acc[6] + b1.z;  o1.w = di * acc[7] + b1.w;
    float* op = out + (size_t)node * CH + c15 * 8;
    *(float4*)op = o0;
    *(float4*)(op + 4) = o1;
}

// ---- launch -------------------------------------------------------------

extern "C" void kernel_launch(void* const* d_in, const int* in_sizes, int n_in,
                              void* d_out, int out_size, void* d_ws, size_t ws_size,
                              hipStream_t stream) {
    const float* x  = (const float*)d_in[0];
    const float* Wm = (const float*)d_in[1];
    const float* b  = (const float*)d_in[2];
    const int*   ei = (const int*)d_in[3];
    int N = in_sizes[0] / CH;
    int E = in_sizes[3] / 2;
    const int* src = ei;
    const int* dst = ei + E;
    float* out = (float*)d_out;

    char* w = (char*)d_ws;
    auto alloc = [&](size_t bytes) {
        char* p = w;
        w += (bytes + 255) & ~(size_t)255;
        return p;
    };
    ushort* xwd  = (ushort*)alloc((size_t)N * CH * 2);
    int*    cnt  = (int*)alloc((size_t)N * 4);
    int*    off  = (int*)alloc((size_t)(N + 1) * 4);
    int*    cur  = (int*)alloc((size_t)N * 4);
    int*    csr  = (int*)alloc((size_t)E * 4);
    float*  dinv = (float*)alloc((size_t)N * 4);
    ushort* Wp   = (ushort*)alloc((size_t)16384 * 2);

    hipMemsetAsync(cnt, 0, (size_t)N * 4, stream);
    count_kernel<<<(E + 255) / 256, 256, 0, stream>>>(dst, cnt, E);
    scan_kernel<<<1, 1024, 0, stream>>>(cnt, off, cur, N);
    dinv_kernel<<<(N + 255) / 256, 256, 0, stream>>>(cnt, dinv, N);
    fill_kernel<<<(E + 255) / 256, 256, 0, stream>>>(src, dst, cur, csr, E);
    pack_w<<<8, 256, 0, stream>>>(Wm, Wp);
    gemm_mfma<<<(N + 63) / 64, 256, 0, stream>>>(x, Wp, dinv, xwd, N);
    agg_kernel<<<(N + 15) / 16, 256, 0, stream>>>(xwd, csr, off, dinv, b, out, N);
}

// Round 3
// 157.204 us; speedup vs baseline: 2.2545x; 1.6554x over previous
//
#include <hip/hip_runtime.h>

// GCN layer: out = D^-1/2 (A + I) D^-1/2 (X W) + b
// N=50000, E=800000, 128 ch. MFMA bf16 GEMM + fused dinv scaling + bf16 gather table.
// R2: replaced single-block scan (110us, uncoalesced 1-CU serial) with 3-kernel
// device-wide coalesced scan + fused dinv.

constexpr int CH = 128;
constexpr int SCAN_E = 2048;   // elements per scan block (256 thr x 8)

typedef __attribute__((ext_vector_type(8))) short short8;
typedef __attribute__((ext_vector_type(4))) float f32x4;

static __device__ __forceinline__ ushort f2bf(float f) {
    unsigned u = __float_as_uint(f);
    u += 0x7fff + ((u >> 16) & 1);   // RNE
    return (ushort)(u >> 16);
}

// ---- CSR build ----------------------------------------------------------

__global__ void count_kernel(const int* __restrict__ dst, int* __restrict__ cnt, int E) {
    int e = blockIdx.x * blockDim.x + threadIdx.x;
    if (e < E) atomicAdd(&cnt[dst[e]], 1);
}

__global__ __launch_bounds__(256) void scan_partial(const int* __restrict__ cnt,
                                                    int* __restrict__ bsum, int N) {
    __shared__ int sm[256];
    int t = threadIdx.x;
    int idx = blockIdx.x * SCAN_E + t * 8;
    int s = 0;
    if (idx + 8 <= N) {
        int4 a = *(const int4*)&cnt[idx];
        int4 b = *(const int4*)&cnt[idx + 4];
        s = a.x + a.y + a.z + a.w + b.x + b.y + b.z + b.w;
    } else {
        for (int i = idx; i < N && i < idx + 8; ++i) s += cnt[i];
    }
    sm[t] = s;
    __syncthreads();
    for (int d = 128; d > 0; d >>= 1) {
        if (t < d) sm[t] += sm[t + d];
        __syncthreads();
    }
    if (t == 0) bsum[blockIdx.x] = sm[0];
}

__global__ void scan_bsum(const int* __restrict__ bsum, int* __restrict__ bofs,
                          int NB, int* __restrict__ offN) {
    if (threadIdx.x == 0) {
        int run = 0;
        for (int i = 0; i < NB; ++i) { bofs[i] = run; run += bsum[i]; }
        *offN = run;   // off[N] = E
    }
}

__global__ __launch_bounds__(256) void scan_final(const int* __restrict__ cnt,
        const int* __restrict__ bofs, int* __restrict__ off, int* __restrict__ cur,
        float* __restrict__ dinv, int N) {
    __shared__ int sm[256];
    int t = threadIdx.x;
    int idx = blockIdx.x * SCAN_E + t * 8;
    int v[8];
    bool full = (idx + 8 <= N);
    if (full) {
        int4 a = *(const int4*)&cnt[idx];
        int4 b = *(const int4*)&cnt[idx + 4];
        v[0]=a.x; v[1]=a.y; v[2]=a.z; v[3]=a.w;
        v[4]=b.x; v[5]=b.y; v[6]=b.z; v[7]=b.w;
    } else {
        #pragma unroll
        for (int k = 0; k < 8; ++k) v[k] = (idx + k < N) ? cnt[idx + k] : 0;
    }
    int s = 0;
    #pragma unroll
    for (int k = 0; k < 8; ++k) s += v[k];
    sm[t] = s;
    __syncthreads();
    #pragma unroll
    for (int d = 1; d < 256; d <<= 1) {
        int u = (t >= d) ? sm[t - d] : 0;
        __syncthreads();
        sm[t] += u;
        __syncthreads();
    }
    int run = bofs[blockIdx.x] + sm[t] - s;   // exclusive prefix for this thread
    int o[8];
    #pragma unroll
    for (int k = 0; k < 8; ++k) { o[k] = run; run += v[k]; }
    float dv[8];
    #pragma unroll
    for (int k = 0; k < 8; ++k) dv[k] = rsqrtf((float)(v[k] + 1));   // +1 self loop
    if (full) {
        *(int4*)&off[idx]     = make_int4(o[0], o[1], o[2], o[3]);
        *(int4*)&off[idx + 4] = make_int4(o[4], o[5], o[6], o[7]);
        *(int4*)&cur[idx]     = make_int4(o[0], o[1], o[2], o[3]);
        *(int4*)&cur[idx + 4] = make_int4(o[4], o[5], o[6], o[7]);
        *(float4*)&dinv[idx]     = make_float4(dv[0], dv[1], dv[2], dv[3]);
        *(float4*)&dinv[idx + 4] = make_float4(dv[4], dv[5], dv[6], dv[7]);
    } else {
        for (int k = 0; k < 8 && idx + k < N; ++k) {
            off[idx + k] = o[k]; cur[idx + k] = o[k]; dinv[idx + k] = dv[k];
        }
    }
}

__global__ void fill_kernel(const int* __restrict__ src, const int* __restrict__ dst,
                            int* __restrict__ cur, int* __restrict__ csr, int E) {
    int e = blockIdx.x * blockDim.x + threadIdx.x;
    if (e < E) {
        int p = atomicAdd(&cur[dst[e]], 1);
        csr[p] = src[e];
    }
}

// ---- W pre-pack: fp32 [128][128] -> bf16 transposed, XOR-swizzled -------

__global__ void pack_w(const float* __restrict__ W, ushort* __restrict__ Wp) {
    int tid = blockIdx.x * blockDim.x + threadIdx.x;   // 2048 threads
    if (tid >= 2048) return;
    int col = tid >> 4, chunk = tid & 15;
    ushort tmp[8];
    #pragma unroll
    for (int i = 0; i < 8; ++i)
        tmp[i] = f2bf(W[(size_t)(chunk * 8 + i) * CH + col]);
    int d = col * 16 + (chunk ^ (col & 7));
    *(uint4*)&Wp[(size_t)d * 8] = *(uint4*)tmp;
}

// ---- GEMM: xwd[r][:] = (x[r][:] @ W) * dinv[r], bf16 out ----------------

__global__ __launch_bounds__(256) void gemm_mfma(const float* __restrict__ x,
        const ushort* __restrict__ Wp, const float* __restrict__ dinv,
        ushort* __restrict__ xwd, int N) {
    __shared__ alignas(16) ushort Wlds[16384];   // 32 KB
    int t = threadIdx.x;
    int wv = t >> 6, l = t & 63;
    int c15 = l & 15, kc = l >> 4;               // kc in 0..3
    int row0 = blockIdx.x * 64 + wv * 16;
    int r = row0 + c15;
    bool valid = r < N;

    short8 af[4];
    #pragma unroll
    for (int ks = 0; ks < 4; ++ks) {
        float4 a0 = make_float4(0.f,0.f,0.f,0.f), a1 = a0;
        if (valid) {
            const float* p = x + (size_t)r * CH + ks * 32 + kc * 8;
            a0 = *(const float4*)p;
            a1 = *(const float4*)(p + 4);
        }
        short8 v;
        v[0]=f2bf(a0.x); v[1]=f2bf(a0.y); v[2]=f2bf(a0.z); v[3]=f2bf(a0.w);
        v[4]=f2bf(a1.x); v[5]=f2bf(a1.y); v[6]=f2bf(a1.z); v[7]=f2bf(a1.w);
        af[ks] = v;
    }

    #pragma unroll
    for (int i = 0; i < 8; ++i) {
        int idx = i * 256 + t;
        *(uint4*)&Wlds[idx * 8] = *(const uint4*)&Wp[idx * 8];
    }
    __syncthreads();

    f32x4 acc[8];
    #pragma unroll
    for (int ct = 0; ct < 8; ++ct) { f32x4 z = {0.f,0.f,0.f,0.f}; acc[ct] = z; }

    int swz = l & 7;
    #pragma unroll
    for (int ks = 0; ks < 4; ++ks) {
        #pragma unroll
        for (int ct = 0; ct < 8; ++ct) {
            int col = ct * 16 + c15;
            int idx16 = (col * 16 + ks * 4 + kc) ^ swz;
            short8 bfrag = *(const short8*)&Wlds[idx16 * 8];
            acc[ct] = __builtin_amdgcn_mfma_f32_16x16x32_bf16(af[ks], bfrag, acc[ct], 0, 0, 0);
        }
    }

    float dv[4];
    #pragma unroll
    for (int rr = 0; rr < 4; ++rr) {
        int row = row0 + kc * 4 + rr;
        dv[rr] = (row < N) ? dinv[row] : 0.f;
    }
    __syncthreads();   // all waves done reading Wlds; reuse as bounce buffer

    ushort* bw = Wlds + wv * 2048;   // 16 rows x 128 cols bf16 per wave
    #pragma unroll
    for (int ct = 0; ct < 8; ++ct) {
        #pragma unroll
        for (int rr = 0; rr < 4; ++rr) {
            int row_local = kc * 4 + rr;
            bw[row_local * CH + ct * 16 + c15] = f2bf(acc[ct][rr] * dv[rr]);
        }
    }
    #pragma unroll
    for (int p = 0; p < 4; ++p) {
        int row_local = p * 4 + kc;
        int row = row0 + row_local;
        if (row < N) {
            uint4 vv = *(const uint4*)&bw[row_local * CH + c15 * 8];
            *(uint4*)&xwd[(size_t)row * CH + c15 * 8] = vv;
        }
    }
}

// ---- Aggregation: out[i] = dinv[i] * (sum_j xwd[src_j] + xwd[i]) + b ----

__global__ __launch_bounds__(256) void agg_kernel(const ushort* __restrict__ xwd,
        const int* __restrict__ csr, const int* __restrict__ off,
        const float* __restrict__ dinv, const float* __restrict__ b,
        float* __restrict__ out, int N) {
    int t = threadIdx.x;
    int c15 = t & 15;                      // 16 lanes/node, 8 ch each
    int node = blockIdx.x * 16 + (t >> 4);
    if (node >= N) return;
    int s = off[node], e = off[node + 1];
    float acc[8] = {0.f,0.f,0.f,0.f,0.f,0.f,0.f,0.f};
    const ushort* base = xwd + c15 * 8;

    int sr = (s < e) ? csr[s] : node;
    for (int j = s; j < e; ++j) {
        int nsr = (j + 1 < e) ? csr[j + 1] : node;   // prefetch next index
        uint4 v = *(const uint4*)(base + (size_t)sr * CH);
        acc[0] += __uint_as_float(v.x << 16);
        acc[1] += __uint_as_float(v.x & 0xffff0000u);
        acc[2] += __uint_as_float(v.y << 16);
        acc[3] += __uint_as_float(v.y & 0xffff0000u);
        acc[4] += __uint_as_float(v.z << 16);
        acc[5] += __uint_as_float(v.z & 0xffff0000u);
        acc[6] += __uint_as_float(v.w << 16);
        acc[7] += __uint_as_float(v.w & 0xffff0000u);
        sr = nsr;
    }
    {   // self loop term
        uint4 v = *(const uint4*)(base + (size_t)node * CH);
        acc[0] += __uint_as_float(v.x << 16);
        acc[1] += __uint_as_float(v.x & 0xffff0000u);
        acc[2] += __uint_as_float(v.y << 16);
        acc[3] += __uint_as_float(v.y & 0xffff0000u);
        acc[4] += __uint_as_float(v.z << 16);
        acc[5] += __uint_as_float(v.z & 0xffff0000u);
        acc[6] += __uint_as_float(v.w << 16);
        acc[7] += __uint_as_float(v.w & 0xffff0000u);
    }
    float di = dinv[node];
    float4 b0 = *(const float4*)&b[c15 * 8];
    float4 b1 = *(const float4*)&b[c15 * 8 + 4];
    float4 o0, o1;
    o0.x = di * acc[0] + b0.x;  o0.y = di * acc[1] + b0.y;
    o0.z = di * acc[2] + b0.z;  o0.w = di * acc[3] + b0.w;
    o1.x = di * acc[4] + b1.x;  o1.y = di * acc[5] + b1.y;
    o1.z = di * acc[6] + b1.z;  o1.w = di * acc[7] + b1.w;
    float* op = out + (size_t)node * CH + c15 * 8;
    *(float4*)op = o0;
    *(float4*)(op + 4) = o1;
}

// ---- launch -------------------------------------------------------------

extern "C" void kernel_launch(void* const* d_in, const int* in_sizes, int n_in,
                              void* d_out, int out_size, void* d_ws, size_t ws_size,
                              hipStream_t stream) {
    const float* x  = (const float*)d_in[0];
    const float* Wm = (const float*)d_in[1];
    const float* b  = (const float*)d_in[2];
    const int*   ei = (const int*)d_in[3];
    int N = in_sizes[0] / CH;
    int E = in_sizes[3] / 2;
    const int* src = ei;
    const int* dst = ei + E;
    float* out = (float*)d_out;

    char* w = (char*)d_ws;
    auto alloc = [&](size_t bytes) {
        char* p = w;
        w += (bytes + 255) & ~(size_t)255;
        return p;
    };
    int NB = (N + SCAN_E - 1) / SCAN_E;
    ushort* xwd  = (ushort*)alloc((size_t)N * CH * 2);
    int*    cnt  = (int*)alloc((size_t)N * 4);
    int*    off  = (int*)alloc((size_t)(N + 1) * 4);
    int*    cur  = (int*)alloc((size_t)N * 4);
    int*    csr  = (int*)alloc((size_t)E * 4);
    float*  dinv = (float*)alloc((size_t)N * 4);
    ushort* Wp   = (ushort*)alloc((size_t)16384 * 2);
    int*    bsum = (int*)alloc((size_t)NB * 4);
    int*    bofs = (int*)alloc((size_t)NB * 4);

    hipMemsetAsync(cnt, 0, (size_t)N * 4, stream);
    count_kernel<<<(E + 255) / 256, 256, 0, stream>>>(dst, cnt, E);
    scan_partial<<<NB, 256, 0, stream>>>(cnt, bsum, N);
    scan_bsum<<<1, 64, 0, stream>>>(bsum, bofs, NB, off + N);
    scan_final<<<NB, 256, 0, stream>>>(cnt, bofs, off, cur, dinv, N);
    fill_kernel<<<(E + 255) / 256, 256, 0, stream>>>(src, dst, cur, csr, E);
    pack_w<<<8, 256, 0, stream>>>(Wm, Wp);
    gemm_mfma<<<(N + 63) / 64, 256, 0, stream>>>(x, Wp, dinv, xwd, N);
    agg_kernel<<<(N + 15) / 16, 256, 0, stream>>>(xwd, csr, off, dinv, b, out, N);
}